// Round 1
// baseline (751.581 us; speedup 1.0000x reference)
//
#include <hip/hip_runtime.h>
#include <math.h>

#define DIM   96
#define HEADS 3
#define HD    32
#define NTOK  49
#define NW    64
#define OSPAD 100   // padded row length (floats) for O / out2 staging
#define KVPAD 36    // padded row length for k/v rows: 144 B, 16B-aligned, breaks 32-bank stride

// LDS float layout (15288 floats = 61152 B -> 2 blocks/CU):
//   [0,     4704)  qsT[3*32][49]   (q transposed: conflict-free store/load)
//   [4704,  9996)  ks [3*49][36]
//   [9996, 15288)  vs [3*49][36]
// After sync2 (q,k dead):   os  = [0,4900)      : O rows [49][100]
// After sync3 (vs dead ok): os2 = [4900,9800)   : proj output rows [49][100]

__global__ __launch_bounds__(256, 2)
void winattn_kernel(const float* __restrict__ x,
                    const float* __restrict__ mask,
                    const float* __restrict__ qkv_w,
                    const float* __restrict__ qkv_b,
                    const float* __restrict__ proj_w,
                    const float* __restrict__ proj_b,
                    const float* __restrict__ rpb,
                    const int*   __restrict__ rel,
                    float* __restrict__ out)
{
    __shared__ float lds[15288];
    float* qsT = lds;            // [3*32][49]
    float* ks  = lds + 4704;     // [3*49][36]
    float* vs  = lds + 9996;     // [3*49][36]
    float* os  = lds;            // [49][100], valid after sync2
    float* os2 = lds + 4900;     // [49][100], valid after sync3

    const int tid  = threadIdx.x;
    const int lane = tid & 63;
    const int wave = __builtin_amdgcn_readfirstlane(tid >> 6);
    const int bnw  = blockIdx.x;
    const int win  = bnw & (NW - 1);
    const int row  = (lane < NTOK) ? lane : (NTOK - 1);
    const bool active = (lane < NTOK);

    // ---------------- Phase 1: x row -> registers (96 VGPRs) ----------------
    float xr[DIM];
    {
        const float4* xrow = (const float4*)(x + (size_t)bnw * (NTOK * DIM) + row * DIM);
        #pragma unroll
        for (int c4 = 0; c4 < DIM / 4; ++c4) {
            float4 t = xrow[c4];
            xr[4*c4+0] = t.x; xr[4*c4+1] = t.y; xr[4*c4+2] = t.z; xr[4*c4+3] = t.w;
        }
    }

    // ---------------- Phase 2: qkv = x @ qkv_w^T + b ----------------
    // wave w handles 72 consecutive output columns; weight rows are wave-uniform
    const float scale = 0.17677669529663687f;  // 32^-0.5
    for (int j0 = wave * 72; j0 < wave * 72 + 72; j0 += 4) {
        float a0 = 0.f, a1 = 0.f, a2 = 0.f, a3 = 0.f;
        const float4* w0 = (const float4*)(qkv_w + (j0 + 0) * DIM);
        const float4* w1 = (const float4*)(qkv_w + (j0 + 1) * DIM);
        const float4* w2 = (const float4*)(qkv_w + (j0 + 2) * DIM);
        const float4* w3 = (const float4*)(qkv_w + (j0 + 3) * DIM);
        #pragma unroll
        for (int k4 = 0; k4 < DIM / 4; ++k4) {
            float4 t0 = w0[k4], t1 = w1[k4], t2 = w2[k4], t3 = w3[k4];
            float xa = xr[4*k4+0], xb = xr[4*k4+1], xc = xr[4*k4+2], xd = xr[4*k4+3];
            a0 += xa*t0.x + xb*t0.y + xc*t0.z + xd*t0.w;
            a1 += xa*t1.x + xb*t1.y + xc*t1.z + xd*t1.w;
            a2 += xa*t2.x + xb*t2.y + xc*t2.z + xd*t2.w;
            a3 += xa*t3.x + xb*t3.y + xc*t3.z + xd*t3.w;
        }
        if (active) {
            float r0 = a0 + qkv_b[j0 + 0];
            float r1 = a1 + qkv_b[j0 + 1];
            float r2 = a2 + qkv_b[j0 + 2];
            float r3 = a3 + qkv_b[j0 + 3];
            if (j0 < 96) {                       // q: store transposed, scaled
                qsT[(j0+0) * NTOK + row] = r0 * scale;
                qsT[(j0+1) * NTOK + row] = r1 * scale;
                qsT[(j0+2) * NTOK + row] = r2 * scale;
                qsT[(j0+3) * NTOK + row] = r3 * scale;
            } else if (j0 < 192) {               // k  (j0%4==0 so no head/d-crossing)
                int jj = j0 - 96;
                float* kr = ks + ((jj >> 5) * NTOK + row) * KVPAD + (jj & 31);
                kr[0] = r0; kr[1] = r1; kr[2] = r2; kr[3] = r3;
            } else {                             // v
                int jj = j0 - 192;
                float* vr = vs + ((jj >> 5) * NTOK + row) * KVPAD + (jj & 31);
                vr[0] = r0; vr[1] = r1; vr[2] = r2; vr[3] = r3;
            }
        }
    }
    __syncthreads();   // sync1: q,k,v visible

    // ---------------- Phase 3: S = q k^T + bias + mask; neg-softmax ----------------
    float p[NTOK];
    float inv = 0.f;
    const int h = wave;
    if (wave < HEADS) {
        float qr[HD];
        #pragma unroll
        for (int d = 0; d < HD; ++d) qr[d] = qsT[(h * HD + d) * NTOK + row];

        const float* mrow = mask + ((size_t)win * NTOK + row) * NTOK;
        const int*   rrow = rel + row * NTOK;
        float mx = 0.f;
        #pragma unroll
        for (int j = 0; j < NTOK; ++j) {
            const float4* kr4 = (const float4*)(ks + (h * NTOK + j) * KVPAD);
            float s = 0.f;
            #pragma unroll
            for (int d4 = 0; d4 < HD / 4; ++d4) {
                float4 kf = kr4[d4];
                s += qr[4*d4+0]*kf.x + qr[4*d4+1]*kf.y + qr[4*d4+2]*kf.z + qr[4*d4+3]*kf.w;
            }
            s += rpb[rrow[j] * HEADS + h] + mrow[j];
            p[j] = s;
            mx = fmaxf(mx, fabsf(s));
        }
        float sum = 0.f;
        #pragma unroll
        for (int j = 0; j < NTOK; ++j) {
            float e = __expf(fabsf(p[j]) - mx);
            sum += e;
            p[j] = (p[j] > 0.f) ? e : ((p[j] < 0.f) ? -e : 0.f);
        }
        inv = 1.f / sum;
    }
    __syncthreads();   // sync2: q,k reads done -> os region reusable

    // ---------------- Phase 4: O = P V ----------------
    if (wave < HEADS) {
        float o[HD];
        #pragma unroll
        for (int d = 0; d < HD; ++d) o[d] = 0.f;
        #pragma unroll
        for (int j = 0; j < NTOK; ++j) {
            const float4* vr4 = (const float4*)(vs + (h * NTOK + j) * KVPAD);
            float pj = p[j];
            #pragma unroll
            for (int d4 = 0; d4 < HD / 4; ++d4) {
                float4 vf = vr4[d4];
                o[4*d4+0] += pj * vf.x; o[4*d4+1] += pj * vf.y;
                o[4*d4+2] += pj * vf.z; o[4*d4+3] += pj * vf.w;
            }
        }
        if (active) {
            #pragma unroll
            for (int d4 = 0; d4 < HD / 4; ++d4) {
                float4 t;
                t.x = o[4*d4+0] * inv; t.y = o[4*d4+1] * inv;
                t.z = o[4*d4+2] * inv; t.w = o[4*d4+3] * inv;
                *(float4*)(os + row * OSPAD + h * HD + 4 * d4) = t;
            }
        }
    }
    __syncthreads();   // sync3: O complete, v dead

    // ---------------- Phase 5: out2 = O @ proj_w^T + b ----------------
    {
        float orow[DIM];
        const float4* osr = (const float4*)(os + row * OSPAD);
        #pragma unroll
        for (int c4 = 0; c4 < DIM / 4; ++c4) {
            float4 t = osr[c4];
            orow[4*c4+0] = t.x; orow[4*c4+1] = t.y; orow[4*c4+2] = t.z; orow[4*c4+3] = t.w;
        }
        for (int c0 = wave * 24; c0 < wave * 24 + 24; c0 += 4) {
            float a0 = 0.f, a1 = 0.f, a2 = 0.f, a3 = 0.f;
            const float4* w0 = (const float4*)(proj_w + (c0 + 0) * DIM);
            const float4* w1 = (const float4*)(proj_w + (c0 + 1) * DIM);
            const float4* w2 = (const float4*)(proj_w + (c0 + 2) * DIM);
            const float4* w3 = (const float4*)(proj_w + (c0 + 3) * DIM);
            #pragma unroll
            for (int k4 = 0; k4 < DIM / 4; ++k4) {
                float4 t0 = w0[k4], t1 = w1[k4], t2 = w2[k4], t3 = w3[k4];
                float xa = orow[4*k4+0], xb = orow[4*k4+1], xc = orow[4*k4+2], xd = orow[4*k4+3];
                a0 += xa*t0.x + xb*t0.y + xc*t0.z + xd*t0.w;
                a1 += xa*t1.x + xb*t1.y + xc*t1.z + xd*t1.w;
                a2 += xa*t2.x + xb*t2.y + xc*t2.z + xd*t2.w;
                a3 += xa*t3.x + xb*t3.y + xc*t3.z + xd*t3.w;
            }
            if (active) {
                float4 r;
                r.x = a0 + proj_b[c0 + 0];
                r.y = a1 + proj_b[c0 + 1];
                r.z = a2 + proj_b[c0 + 2];
                r.w = a3 + proj_b[c0 + 3];
                *(float4*)(os2 + row * OSPAD + c0) = r;
            }
        }
    }
    __syncthreads();   // sync4: out2 staged

    // ---------------- Phase 6: coalesced writeout ----------------
    {
        float4* outp = (float4*)(out + (size_t)bnw * (NTOK * DIM));
        for (int m4 = tid; m4 < (NTOK * DIM) / 4; m4 += 256) {
            int i = m4 / (DIM / 4);
            int t = m4 - i * (DIM / 4);
            outp[m4] = *(const float4*)(os2 + i * OSPAD + 4 * t);
        }
    }
}

extern "C" void kernel_launch(void* const* d_in, const int* in_sizes, int n_in,
                              void* d_out, int out_size, void* d_ws, size_t ws_size,
                              hipStream_t stream) {
    const float* x      = (const float*)d_in[0];
    const float* mask   = (const float*)d_in[1];
    const float* qkv_w  = (const float*)d_in[2];
    const float* qkv_b  = (const float*)d_in[3];
    const float* proj_w = (const float*)d_in[4];
    const float* proj_b = (const float*)d_in[5];
    const float* rpb    = (const float*)d_in[6];
    const int*   rel    = (const int*)d_in[7];
    float* outp         = (float*)d_out;

    const int n_windows = in_sizes[0] / (NTOK * DIM);   // 4096
    winattn_kernel<<<n_windows, 256, 0, stream>>>(x, mask, qkv_w, qkv_b,
                                                  proj_w, proj_b, rpb, rel, outp);
}

// Round 3
// 422.142 us; speedup vs baseline: 1.7804x; 1.7804x over previous
//
#include <hip/hip_runtime.h>
#include <math.h>

#define DIM    96
#define HEADS  3
#define HD     32
#define NTOK   49
#define NWIN   64
#define SCALE  0.17677669529663687f

// ---- LDS layout (unsigned shorts) ----
// Q  [3][64][40]  @ 0       (7680)   bf16, token-major, pitch 40 (80 B, 16B-mult)
// K  [3][64][32]  @ 7680    (6144)   bf16, pitch 32
// VT [3][32][72]  @ 13824   (6912)   bf16, d-major (tokens padded to 72)
// O  [64][96]     @ 20736   (6144)   bf16
// P  [3][64][72]  @ 0       (13824)  aliases Q+K exactly (after barrier)
// outstage [49][100] f32 @ 0 (9800 shorts) aliases P (after barrier)
// total: 26880 shorts = 53760 B -> 3 blocks/CU
#define Q_OFF  0
#define QP     40
#define QH     2560
#define K_OFF  7680
#define KP     32
#define KH     2048
#define VT_OFF 13824
#define VP     72
#define VH     2304
#define O_OFF  20736
#define OP     96
#define P_OFF  0
#define PP     72
#define PH     4608
#define LDS_SHORTS 26880

typedef float  f32x4  __attribute__((ext_vector_type(4)));
typedef __bf16 bf16x8 __attribute__((ext_vector_type(8)));
typedef short  short8 __attribute__((ext_vector_type(8)));

union U8 { short8 s; bf16x8 b; };

__device__ __forceinline__ unsigned short f2bf(float f) {
    __bf16 h = (__bf16)f;
    union { __bf16 h; unsigned short u; } v; v.h = h; return v.u;
}

// load 8 consecutive f32 from global, convert to bf16 frag
__device__ __forceinline__ void ldcvt_g(const float* __restrict__ p, U8& u) {
    float4 f0 = *(const float4*)p;
    float4 f1 = *(const float4*)(p + 4);
    u.b[0] = (__bf16)f0.x; u.b[1] = (__bf16)f0.y; u.b[2] = (__bf16)f0.z; u.b[3] = (__bf16)f0.w;
    u.b[4] = (__bf16)f1.x; u.b[5] = (__bf16)f1.y; u.b[6] = (__bf16)f1.z; u.b[7] = (__bf16)f1.w;
}

// ---- bias precompute: biasT[h][i][j] = rpb[rel[i*49+j]*3 + h] ----
__global__ __launch_bounds__(256)
void bias_build(const float* __restrict__ rpb, const int* __restrict__ rel,
                float* __restrict__ bias) {
    int t = blockIdx.x * 256 + threadIdx.x;
    if (t < HEADS * NTOK * NTOK) {
        int h = t / (NTOK * NTOK), ij = t % (NTOK * NTOK);
        bias[t] = rpb[rel[ij] * HEADS + h];
    }
}

__global__ __launch_bounds__(256, 3)
void winattn_mfma(const float* __restrict__ x,
                  const float* __restrict__ mask,
                  const float* __restrict__ qkv_w,
                  const float* __restrict__ qkv_b,
                  const float* __restrict__ proj_w,
                  const float* __restrict__ proj_b,
                  const float* __restrict__ biasT,
                  float* __restrict__ out)
{
    __shared__ __align__(16) unsigned short sbuf[LDS_SHORTS];
    float* outstage = (float*)sbuf;   // [49][100] f32, aliases P region (phase-ordered)

    const int tid  = threadIdx.x;
    const int lane = tid & 63;
    const int wave = __builtin_amdgcn_readfirstlane(tid >> 6);
    const int l15  = lane & 15;
    const int quad = lane >> 4;
    const int bnw  = blockIdx.x;
    const int win  = bnw & (NWIN - 1);

    // ================= Phase 1: QKV = x @ qkv_w^T + b (MFMA) =================
    {
        const float* xw = x + (size_t)bnw * (NTOK * DIM);
        const int arow = 16 * wave + l15;           // A row (token), wave = m-tile
        const bool av = (arow < NTOK);
        U8 af[3];
        #pragma unroll
        for (int s = 0; s < 3; ++s) {
            if (av) {
                ldcvt_g(xw + arow * DIM + 32 * s + quad * 8, af[s]);
            } else {
                #pragma unroll
                for (int j = 0; j < 8; ++j) af[s].b[j] = (__bf16)0.0f;
            }
        }
        for (int t = 0; t < 18; ++t) {
            f32x4 acc = {0.f, 0.f, 0.f, 0.f};
            const int col = 16 * t + l15;
            #pragma unroll
            for (int s = 0; s < 3; ++s) {
                U8 bf_;
                ldcvt_g(qkv_w + col * DIM + 32 * s + quad * 8, bf_);
                acc = __builtin_amdgcn_mfma_f32_16x16x32_bf16(af[s].b, bf_.b, acc, 0, 0, 0);
            }
            const float bb = qkv_b[col];
            const int row0 = 16 * wave + quad * 4;
            if (t < 6) {              // q (scaled), token-major
                int h = col >> 5, d = col & 31;
                #pragma unroll
                for (int r = 0; r < 4; ++r)
                    sbuf[Q_OFF + h * QH + (row0 + r) * QP + d] = f2bf((acc[r] + bb) * SCALE);
            } else if (t < 12) {      // k, token-major
                int c = col - 96; int h = c >> 5, d = c & 31;
                #pragma unroll
                for (int r = 0; r < 4; ++r)
                    sbuf[K_OFF + h * KH + (row0 + r) * KP + d] = f2bf(acc[r] + bb);
            } else {                  // v transposed: VT[h][d][token]
                int c = col - 192; int h = c >> 5, d = c & 31;
                ushort4 pk;
                pk.x = f2bf(acc[0] + bb); pk.y = f2bf(acc[1] + bb);
                pk.z = f2bf(acc[2] + bb); pk.w = f2bf(acc[3] + bb);
                *(ushort4*)(sbuf + VT_OFF + h * VH + d * VP + row0) = pk;
            }
        }
    }
    __syncthreads();   // Q,K,VT visible

    // ========= Phase 2: S = qk^T + bias + mask, in-register neg-softmax =========
    // 12 units (h, mtile) over 4 waves; wave w owns uids {w, w+4, w+8}
    float Pheld[3][4][4];   // [unit][t][r]
    float invh[3][4];       // [unit][r]
    #pragma unroll
    for (int u = 0; u < 3; ++u) {
        const int uid = wave + 4 * u;
        const int h = uid % 3, mt = uid / 3;
        U8 qf; qf.s = *(const short8*)(sbuf + Q_OFF + h * QH + (16 * mt + l15) * QP + quad * 8);
        f32x4 st[4];
        #pragma unroll
        for (int t = 0; t < 4; ++t) {
            U8 kf; kf.s = *(const short8*)(sbuf + K_OFF + h * KH + (16 * t + l15) * KP + quad * 8);
            f32x4 z = {0.f, 0.f, 0.f, 0.f};
            st[t] = __builtin_amdgcn_mfma_f32_16x16x32_bf16(qf.b, kf.b, z, 0, 0, 0);
        }
        const float* bh = biasT + h * (NTOK * NTOK);
        const float* mw = mask + (size_t)win * (NTOK * NTOK);
        float sv[4][4];
        float mx[4] = {-1e30f, -1e30f, -1e30f, -1e30f};
        bool cok[4];
        #pragma unroll
        for (int t = 0; t < 4; ++t) {
            const int colr = 16 * t + l15;
            cok[t] = (colr < NTOK);
            const int colc = cok[t] ? colr : (NTOK - 1);
            #pragma unroll
            for (int r = 0; r < 4; ++r) {
                int rowr = 16 * mt + quad * 4 + r;
                int rowc = (rowr < NTOK) ? rowr : (NTOK - 1);
                float s = st[t][r] + bh[rowc * NTOK + colc] + mw[rowc * NTOK + colc];
                sv[t][r] = s;
                float aa = cok[t] ? fabsf(s) : -1e30f;
                mx[r] = fmaxf(mx[r], aa);
            }
        }
        #pragma unroll
        for (int r = 0; r < 4; ++r) {
            #pragma unroll
            for (int m = 1; m < 16; m <<= 1)
                mx[r] = fmaxf(mx[r], __shfl_xor(mx[r], m));
        }
        float sum[4] = {0.f, 0.f, 0.f, 0.f};
        #pragma unroll
        for (int t = 0; t < 4; ++t) {
            #pragma unroll
            for (int r = 0; r < 4; ++r) {
                float s = sv[t][r];
                float e = cok[t] ? __expf(fabsf(s) - mx[r]) : 0.f;
                sum[r] += e;
                Pheld[u][t][r] = (s > 0.f) ? e : ((s < 0.f) ? -e : 0.f);
            }
        }
        #pragma unroll
        for (int r = 0; r < 4; ++r) {
            #pragma unroll
            for (int m = 1; m < 16; m <<= 1)
                sum[r] += __shfl_xor(sum[r], m);
            invh[u][r] = 1.f / sum[r];
        }
    }
    __syncthreads();   // all Q/K reads done -> P may overwrite Q+K region

    // ---- store P (bf16, A-layout rows; masked cols already 0) ----
    #pragma unroll
    for (int u = 0; u < 3; ++u) {
        const int uid = wave + 4 * u;
        const int h = uid % 3, mt = uid / 3;
        #pragma unroll
        for (int t = 0; t < 4; ++t) {
            const int col = 16 * t + l15;
            #pragma unroll
            for (int r = 0; r < 4; ++r) {
                const int row = 16 * mt + quad * 4 + r;
                sbuf[P_OFF + h * PH + row * PP + col] = f2bf(Pheld[u][t][r]);
            }
        }
    }
    __syncthreads();   // P visible

    // ================= Phase 3: O = P V (MFMA), scale by 1/sum =================
    #pragma unroll
    for (int u = 0; u < 3; ++u) {
        const int uid = wave + 4 * u;
        const int h = uid % 3, mt = uid / 3;
        U8 pa[2];
        #pragma unroll
        for (int s = 0; s < 2; ++s)
            pa[s].s = *(const short8*)(sbuf + P_OFF + h * PH + (16 * mt + l15) * PP + 32 * s + quad * 8);
        #pragma unroll
        for (int tp = 0; tp < 2; ++tp) {
            f32x4 o = {0.f, 0.f, 0.f, 0.f};
            #pragma unroll
            for (int s = 0; s < 2; ++s) {
                U8 vf; vf.s = *(const short8*)(sbuf + VT_OFF + h * VH + (16 * tp + l15) * VP + 32 * s + quad * 8);
                o = __builtin_amdgcn_mfma_f32_16x16x32_bf16(pa[s].b, vf.b, o, 0, 0, 0);
            }
            const int col = h * HD + 16 * tp + l15;
            #pragma unroll
            for (int r = 0; r < 4; ++r) {
                const int row = 16 * mt + quad * 4 + r;
                sbuf[O_OFF + row * OP + col] = f2bf(o[r] * invh[u][r]);
            }
        }
    }
    __syncthreads();   // O visible; P/VT dead -> outstage may use region 0

    // ================= Phase 4: out = O @ proj_w^T + b (MFMA) =================
    {
        U8 af[3];
        #pragma unroll
        for (int s = 0; s < 3; ++s)
            af[s].s = *(const short8*)(sbuf + O_OFF + (16 * wave + l15) * OP + 32 * s + quad * 8);
        #pragma unroll
        for (int t = 0; t < 6; ++t) {
            f32x4 acc = {0.f, 0.f, 0.f, 0.f};
            const int col = 16 * t + l15;
            #pragma unroll
            for (int s = 0; s < 3; ++s) {
                U8 bf_;
                ldcvt_g(proj_w + col * DIM + 32 * s + quad * 8, bf_);
                acc = __builtin_amdgcn_mfma_f32_16x16x32_bf16(af[s].b, bf_.b, acc, 0, 0, 0);
            }
            const float pb = proj_b[col];
            #pragma unroll
            for (int r = 0; r < 4; ++r) {
                const int row = 16 * wave + quad * 4 + r;
                if (row < NTOK)
                    outstage[row * 100 + col] = acc[r] + pb;
            }
        }
    }
    __syncthreads();   // outstage complete

    // ================= Phase 5: coalesced writeout =================
    {
        float4* outp = (float4*)(out + (size_t)bnw * (NTOK * DIM));
        for (int m4 = tid; m4 < (NTOK * DIM) / 4; m4 += 256) {
            int i = m4 / (DIM / 4);
            int t = m4 - i * (DIM / 4);
            outp[m4] = *(const float4*)(outstage + i * 100 + 4 * t);
        }
    }
}

extern "C" void kernel_launch(void* const* d_in, const int* in_sizes, int n_in,
                              void* d_out, int out_size, void* d_ws, size_t ws_size,
                              hipStream_t stream) {
    const float* x      = (const float*)d_in[0];
    const float* mask   = (const float*)d_in[1];
    const float* qkv_w  = (const float*)d_in[2];
    const float* qkv_b  = (const float*)d_in[3];
    const float* proj_w = (const float*)d_in[4];
    const float* proj_b = (const float*)d_in[5];
    const float* rpb    = (const float*)d_in[6];
    const int*   rel    = (const int*)d_in[7];
    float* outp         = (float*)d_out;
    float* biasT        = (float*)d_ws;   // 3*49*49 f32 = 28812 B

    bias_build<<<(HEADS * NTOK * NTOK + 255) / 256, 256, 0, stream>>>(rpb, rel, biasT);

    const int n_windows = in_sizes[0] / (NTOK * DIM);   // 4096
    winattn_mfma<<<n_windows, 256, 0, stream>>>(x, mask, qkv_w, qkv_b,
                                                proj_w, proj_b, biasT, outp);
}